// Round 7
// baseline (65.215 us; speedup 1.0000x reference)
//
#include <hip/hip_runtime.h>
#include <math.h>

#define WIDTH    1024
#define NCOLS    8193        // N + 1 (bias in last column)
#define N_LAYERS 8
#define NBLOCKS  64
#define TPB      1024
#define WPB      16          // waves per block; wave w owns row bid*16+w

typedef __attribute__((ext_vector_type(4))) float f32x4;
typedef unsigned long long u64;

#define TAGOF(l) (0x51A7E500u + (unsigned)(l))

// weights (cached path, dwordx4 at 4B alignment — HW-supported, proven R4/R6)
// + bias, fully waited in-statement. Early-clobber on all outputs (R5 lesson).
__device__ __forceinline__ void ld_w_wait(const float* wp, const float* bp,
        f32x4& w0, f32x4& w1, f32x4& w2, f32x4& w3, float& bi)
{
    asm volatile(
        "global_load_dwordx4 %0, %5, off\n\t"
        "global_load_dwordx4 %1, %5, off offset:16\n\t"
        "global_load_dwordx4 %2, %5, off offset:32\n\t"
        "global_load_dwordx4 %3, %5, off offset:48\n\t"
        "global_load_dword   %4, %6, off\n\t"
        "s_waitcnt vmcnt(0)"
        : "=&v"(w0), "=&v"(w1), "=&v"(w2), "=&v"(w3), "=&v"(bi)
        : "v"(wp), "v"(bp)
        : "memory");
}

// publish one row's value to ALL 64 block-regions: every lane holds the same
// h after the butterfly; lane i deposits the copy into region i. One wave-store.
__device__ __forceinline__ void publish(u64* buf, unsigned tag, int row, float h)
{
    const int lane = threadIdx.x & 63;
    u64 pk = ((u64)tag << 32) | (u64)__float_as_uint(h);
    u64* p = buf + ((size_t)lane * WIDTH + row);
    asm volatile("global_store_dwordx2 %0, %1, off sc0 sc1"
                 :: "v"(p), "v"(pk) : "memory");
}

__device__ __forceinline__ float dot4(const f32x4 w[4], const f32x4 a[4])
{
    float s = 0.f;
    #pragma unroll
    for (int j = 0; j < 4; ++j)
        s += w[j].x * a[j].x + w[j].y * a[j].y
           + w[j].z * a[j].z + w[j].w * a[j].w;
    return s;
}

// Fused 7-layer MLP. Sync = tagged coherent packets replicated per consumer
// block (exclusive poll lines, no fences, no atomics, no flags, no memset).
__global__ __launch_bounds__(TPB) void mlp_fused_kernel(
    const float* __restrict__ P,      // (8192 x 8193)
    const float* __restrict__ x,      // (1024,)
    float* __restrict__ out,          // (1024,)
    u64* __restrict__ buf0,           // copies[64 regions][1024 rows]
    u64* __restrict__ buf1)           // ping-pong partner
{
    const int wid  = threadIdx.x >> 6;
    const int lane = threadIdx.x & 63;
    const int bid  = blockIdx.x;
    const int row  = bid * WPB + wid;            // 0..1023

    __shared__ __align__(16) float act[WIDTH];

    u64* bufs[2] = { buf0, buf1 };               // layer l writes bufs[l&1]

    // ---------------- layer 1: consume x directly ----------------
    {
        const size_t rb = (size_t)(WIDTH + row) * (size_t)NCOLS;
        f32x4 w[4]; float bi;
        ld_w_wait(P + rb + lane * 16, P + rb + (NCOLS - 1),
                  w[0], w[1], w[2], w[3], bi);
        const f32x4* xv = (const f32x4*)x + lane * 4;   // x is 16B-aligned
        f32x4 a[4];
        #pragma unroll
        for (int j = 0; j < 4; ++j) a[j] = xv[j];
        float s = dot4(w, a);
        #pragma unroll
        for (int off = 32; off > 0; off >>= 1) s += __shfl_xor(s, off, 64);
        float aff = s + bi;
        float h = aff / (1.f + __expf(-aff));           // silu
        publish(bufs[1], TAGOF(1), row, h);             // all lanes scatter
    }

    // ---------------- layers 2..7 ----------------
    #pragma unroll
    for (int l = 2; l < N_LAYERS; ++l) {
        const bool last = (l == N_LAYERS - 1);
        const size_t rb = (size_t)(l * WIDTH + row) * (size_t)NCOLS;

        // this layer's weights (L2-hot after first replay), fully waited
        f32x4 w[4]; float bi;
        ld_w_wait(P + rb + (size_t)(l - 1) * WIDTH + lane * 16,
                  P + rb + (NCOLS - 1), w[0], w[1], w[2], w[3], bi);

        // wave w polls its 64-slot segment of THIS block's private region.
        // Exclusive lines -> unloaded MALL latency, no contention.
        {
            const u64* sp = bufs[(l - 1) & 1]
                          + (size_t)bid * WIDTH + wid * 64 + lane;
            const unsigned tag = TAGOF(l - 1);
            u64 pk;
            do {
                asm volatile(
                    "global_load_dwordx2 %0, %1, off sc0 sc1\n\t"
                    "s_waitcnt vmcnt(0)"
                    : "=&v"(pk) : "v"(sp) : "memory");
            } while (!__all((unsigned)(pk >> 32) == tag));
            act[wid * 64 + lane] = __uint_as_float((unsigned)pk);
        }
        __syncthreads();                                 // all segments in LDS

        const f32x4* av = (const f32x4*)act + lane * 4;
        f32x4 a[4];
        #pragma unroll
        for (int j = 0; j < 4; ++j) a[j] = av[j];
        float s = dot4(w, a);
        #pragma unroll
        for (int off = 32; off > 0; off >>= 1) s += __shfl_xor(s, off, 64);
        float aff = s + bi;

        if (last) {
            if (lane == 0) out[row] = aff;               // flushed at kernel end
        } else {
            float h = aff / (1.f + __expf(-aff));        // silu
            publish(bufs[l & 1], TAGOF(l), row, h);
            __syncthreads();       // protect act[] from next layer's writes
        }
    }
}

extern "C" void kernel_launch(void* const* d_in, const int* in_sizes, int n_in,
                              void* d_out, int out_size, void* d_ws, size_t ws_size,
                              hipStream_t stream) {
    const float* x = (const float*)d_in[0];   // (1024,)
    const float* P = (const float*)d_in[1];   // (8192, 8193)
    float* out = (float*)d_out;               // (1024,)

    u64* buf0 = (u64*)d_ws;                               // 64*1024*8B = 512KB
    u64* buf1 = buf0 + (size_t)NBLOCKS * WIDTH;           // 512KB

    void* args[] = { (void*)&P, (void*)&x, (void*)&out, (void*)&buf0, (void*)&buf1 };
    hipLaunchCooperativeKernel((const void*)mlp_fused_kernel,
                               dim3(NBLOCKS), dim3(TPB), args, 0, stream);
}

// Round 8
// 45.401 us; speedup vs baseline: 1.4364x; 1.4364x over previous
//
#include <hip/hip_runtime.h>
#include <math.h>

#define WIDTH    1024
#define NCOLS    8193        // N + 1 (bias in last column, global col 8192)
#define N_LAYERS 8
#define NBLOCKS  64
#define TPB      1024
#define WPB      16          // waves per block; wave w owns row bid*16+w
#define NREG     8           // activation replicas (fan-out 8, share 8)

typedef unsigned long long u64;
#define TAGOF(l) (0x51A7E500u + (unsigned)(l))

// coherent 8B tagged-slot ops (L1/L2-bypass, served at the coherence point).
// In-statement waitcnt + early-clobber output: self-contained, no cross-
// statement scoreboard hazards (R5 lesson).
__device__ __forceinline__ u64 ld_slot(const u64* p) {
    u64 v;
    asm volatile("global_load_dwordx2 %0, %1, off sc0 sc1\n\t"
                 "s_waitcnt vmcnt(0)"
                 : "=&v"(v) : "v"(p) : "memory");
    return v;
}
__device__ __forceinline__ void st_slot(u64* p, u64 v) {
    asm volatile("global_store_dwordx2 %0, %1, off sc0 sc1"
                 :: "v"(p), "v"(v) : "memory");
}

// Fused 7-layer MLP. Sync = tagged coherent packets, 8 replicated regions,
// coalesced 128B publish chunks, one 8KB consume per block staged via LDS.
// Lane owns strided columns {lane + 64k}: coalesced dword weight loads,
// conflict-free ds_read_b32 activation reads.
__global__ __launch_bounds__(TPB) void mlp_fused_kernel(
    const float* __restrict__ P,      // (8192 x 8193)
    const float* __restrict__ x,      // (1024,)
    float* __restrict__ out,          // (1024,)
    u64* __restrict__ buf0,           // [NREG][1024] slots, layers 2,4,6
    u64* __restrict__ buf1)           // [NREG][1024] slots, layers 1,3,5
{
    const int wid  = threadIdx.x >> 6;
    const int lane = threadIdx.x & 63;
    const int bid  = blockIdx.x;
    const int row  = bid * WPB + wid;            // 0..1023

    __shared__ float act[WIDTH];                 // gathered previous layer
    __shared__ float hblk[WPB];                  // this block's 16 outputs

    u64* bufs[2] = { buf0, buf1 };               // layer l publishes bufs[l&1]

    // ---------------- layer 1: consume x from global ----------------
    {
        const float* wrow = P + (size_t)(WIDTH + row) * NCOLS;   // (l-1)*W = 0
        float s = 0.f;
        #pragma unroll
        for (int k = 0; k < 16; ++k)
            s += wrow[lane + (k << 6)] * x[lane + (k << 6)];
        #pragma unroll
        for (int off = 32; off > 0; off >>= 1) s += __shfl_xor(s, off, 64);
        float aff = s + wrow[WIDTH * (N_LAYERS - 1) + WIDTH];    // col 8192: bias
        float h = aff / (1.f + __expf(-aff));                    // silu
        if (lane == 0) hblk[wid] = h;
    }
    __syncthreads();     // hblk ready; (no act[] yet to protect)

    // ---------------- layers 2..7 ----------------
    #pragma unroll
    for (int l = 2; l < N_LAYERS; ++l) {
        const bool last = (l == N_LAYERS - 1);
        u64* wbuf = bufs[(l - 1) & 1];
        const unsigned tag = TAGOF(l - 1);

        // publish previous layer: 8 waves x 16 lanes; each wave stores the
        // block's 16 packets CONTIGUOUSLY (128B chunk) into its region.
        if (wid < NREG && lane < WPB) {
            u64 pk = ((u64)tag << 32) | (u64)__float_as_uint(hblk[lane]);
            st_slot(wbuf + (size_t)wid * WIDTH + bid * WPB + lane, pk);
        }

        // this layer's weights: plain cached loads (compiler schedules them
        // under the publish->observe window; waited naturally before use)
        const float* wrow = P + (size_t)(l * WIDTH + row) * NCOLS
                              + (size_t)(l - 1) * WIDTH;
        float w[16];
        #pragma unroll
        for (int k = 0; k < 16; ++k) w[k] = wrow[lane + (k << 6)];
        const float bi = P[(size_t)(l * WIDTH + row) * NCOLS + (NCOLS - 1)];

        // poll my region's segment: data-is-the-flag, 8B/lane/round
        {
            const u64* sp = wbuf + (size_t)(bid & (NREG - 1)) * WIDTH
                          + (wid << 6) + lane;
            u64 pk;
            do { pk = ld_slot(sp); } while (!__all((unsigned)(pk >> 32) == tag));
            act[(wid << 6) + lane] = __uint_as_float((unsigned)pk);
        }
        __syncthreads();     // act[] fully staged

        // dot: conflict-free ds_read_b32 (stride 4B across lanes)
        float s = 0.f;
        #pragma unroll
        for (int k = 0; k < 16; ++k)
            s += w[k] * act[lane + (k << 6)];
        #pragma unroll
        for (int off = 32; off > 0; off >>= 1) s += __shfl_xor(s, off, 64);
        float aff = s + bi;

        if (last) {
            if (lane == 0) out[row] = aff;       // flushed at kernel end
        } else {
            float h = aff / (1.f + __expf(-aff));
            if (lane == 0) hblk[wid] = h;
            __syncthreads();   // act reads done + hblk ready -> next iter may
                               // publish hblk and overwrite act[]
        }
    }
}

extern "C" void kernel_launch(void* const* d_in, const int* in_sizes, int n_in,
                              void* d_out, int out_size, void* d_ws, size_t ws_size,
                              hipStream_t stream) {
    const float* x = (const float*)d_in[0];   // (1024,)
    const float* P = (const float*)d_in[1];   // (8192, 8193)
    float* out = (float*)d_out;               // (1024,)

    u64* buf0 = (u64*)d_ws;                         // 8*1024*8B = 64KB
    u64* buf1 = buf0 + (size_t)NREG * WIDTH;        // 64KB

    // clear tag space (first-call safety; graph node, stream-ordered)
    hipMemsetAsync(buf0, 0, 2 * NREG * WIDTH * sizeof(u64), stream);

    void* args[] = { (void*)&P, (void*)&x, (void*)&out, (void*)&buf0, (void*)&buf1 };
    hipLaunchCooperativeKernel((const void*)mlp_fused_kernel,
                               dim3(NBLOCKS), dim3(TPB), args, 0, stream);
}

// Round 9
// 30.118 us; speedup vs baseline: 2.1653x; 1.5075x over previous
//
#include <hip/hip_runtime.h>
#include <math.h>

#define WIDTH    1024
#define NCOLS    8193        // N + 1 (bias at global col 8192)
#define N_LAYERS 8
#define NBLOCKS  64
#define TPB      1024
#define WPB      16          // waves per block; wave w owns row bid*16+w
#define NREG     8           // activation replicas; block polls region bid&7

typedef unsigned long long u64;
#define TAGOF(l) (0x51A7E500u + (unsigned)(l))

// coherent 8B tagged-slot ops (bypass L1/L2, served at coherence point).
// In-statement waitcnt + early-clobber: self-contained (R5 lesson).
__device__ __forceinline__ u64 ld_slot(const u64* p) {
    u64 v;
    asm volatile("global_load_dwordx2 %0, %1, off sc0 sc1\n\t"
                 "s_waitcnt vmcnt(0)"
                 : "=&v"(v) : "v"(p) : "memory");
    return v;
}
__device__ __forceinline__ void st_slot(u64* p, u64 v) {
    asm volatile("global_store_dwordx2 %0, %1, off sc0 sc1"
                 :: "v"(p), "v"(v) : "memory");
}

// Fused 7-layer MLP. Sync = tagged coherent packets, 8 replicated regions.
// Direct per-wave publish (row streams out the moment it's computed),
// double-buffered LDS act -> ONE __syncthreads per layer.
// PLAIN launch: no cooperative features used; 64 blocks << capacity (512)
// so all blocks are resident and the spin cannot deadlock.
__global__ __launch_bounds__(TPB) void mlp_fused_kernel(
    const float* __restrict__ P,      // (8192 x 8193)
    const float* __restrict__ x,      // (1024,)
    float* __restrict__ out,          // (1024,)
    u64* __restrict__ buf0,           // [NREG][1024] slots, layers 2,4,6
    u64* __restrict__ buf1)           // [NREG][1024] slots, layers 1,3,5
{
    const int wid  = threadIdx.x >> 6;
    const int lane = threadIdx.x & 63;
    const int bid  = blockIdx.x;
    const int row  = bid * WPB + wid;            // 0..1023

    __shared__ float act[2][WIDTH];              // ping-pong staging
    u64* bufs[2] = { buf0, buf1 };               // layer l publishes bufs[l&1]

    // ---------------- layer 1: consume x from global (cached) ----------------
    {
        const float* wrow = P + (size_t)(WIDTH + row) * NCOLS;   // (l-1)*W = 0
        float s = 0.f;
        #pragma unroll
        for (int k = 0; k < 16; ++k)
            s += wrow[lane + (k << 6)] * x[lane + (k << 6)];
        #pragma unroll
        for (int off = 32; off > 0; off >>= 1) s += __shfl_xor(s, off, 64);
        float aff = s + wrow[8192];                              // bias
        float h = aff / (1.f + __expf(-aff));                    // silu
        // direct publish: lanes 0..7 deposit this row's packet in 8 regions
        u64 pk = ((u64)TAGOF(1) << 32) | (u64)__float_as_uint(h);
        if (lane < NREG)
            st_slot(bufs[1] + (size_t)lane * WIDTH + row, pk);
    }

    // ---------------- layers 2..7 ----------------
    #pragma unroll
    for (int l = 2; l < N_LAYERS; ++l) {
        const bool last = (l == N_LAYERS - 1);
        u64* wbuf = bufs[(l - 1) & 1];
        const unsigned tag = TAGOF(l - 1);
        const int cur = l & 1;

        const size_t rb = (size_t)(l * WIDTH + row) * NCOLS;
        const float* wrow = P + rb + (size_t)(l - 1) * WIDTH;

        // weights: plain cached loads, issued now, consumed after the poll
        // (they drain under the poll's vmcnt(0) -> overlapped with sync)
        float w[16];
        #pragma unroll
        for (int k = 0; k < 16; ++k) w[k] = wrow[lane + (k << 6)];
        const float bi = P[rb + 8192];

        // poll my region's segment: data-is-the-flag, 8B/lane/round
        {
            const u64* sp = wbuf + (size_t)(bid & (NREG - 1)) * WIDTH
                          + (wid << 6) + lane;
            u64 pk;
            do { pk = ld_slot(sp); } while (!__all((unsigned)(pk >> 32) == tag));
            act[cur][(wid << 6) + lane] = __uint_as_float((unsigned)pk);
        }
        // ONE barrier per layer. Safe with dbuf: a wave writes act[cur^1]
        // (next layer's stage) only after passing the NEXT iteration's
        // barrier, which requires every wave to have finished this layer's
        // dot-read of act[cur^1... ] — write/read of the same buffer are
        // always separated by a barrier in between.
        __syncthreads();

        // dot: conflict-free ds_read_b32 (lane-consecutive)
        float s = 0.f;
        #pragma unroll
        for (int k = 0; k < 16; ++k)
            s += w[k] * act[cur][lane + (k << 6)];
        #pragma unroll
        for (int off = 32; off > 0; off >>= 1) s += __shfl_xor(s, off, 64);
        float aff = s + bi;

        if (last) {
            if (lane == 0) out[row] = aff;       // flushed at kernel end
        } else {
            float h = aff / (1.f + __expf(-aff));
            u64 pk = ((u64)TAGOF(l) << 32) | (u64)__float_as_uint(h);
            if (lane < NREG)
                st_slot(bufs[l & 1] + (size_t)lane * WIDTH + row, pk);
        }
    }
}

extern "C" void kernel_launch(void* const* d_in, const int* in_sizes, int n_in,
                              void* d_out, int out_size, void* d_ws, size_t ws_size,
                              hipStream_t stream) {
    const float* x = (const float*)d_in[0];   // (1024,)
    const float* P = (const float*)d_in[1];   // (8192, 8193)
    float* out = (float*)d_out;               // (1024,)

    u64* buf0 = (u64*)d_ws;                         // 8*1024*8B = 64KB
    u64* buf1 = buf0 + (size_t)NREG * WIDTH;        // 64KB

    // clear tag space (first-call safety; graph node, stream-ordered)
    hipMemsetAsync(buf0, 0, 2 * NREG * WIDTH * sizeof(u64), stream);

    mlp_fused_kernel<<<dim3(NBLOCKS), dim3(TPB), 0, stream>>>(
        P, x, out, buf0, buf1);
}